// Round 4
// baseline (442.840 us; speedup 1.0000x reference)
//
#include <hip/hip_runtime.h>
#include <hip/hip_bf16.h>
#include <stdint.h>

#define NB 4
#define NK 64
#define NL 128
#define ND 768
#define NBK (NB*NK)        // 256
#define NROW (NBK*NL)      // 32768
#define LD2 (NL*ND)        // 98304
#define EPSF 1e-8f
#define THETA 2e-3f        // candidate window (>>75 sigma of split-bf16 error)
#define CAP 16384

typedef __bf16 bf16x8 __attribute__((ext_vector_type(8)));
typedef float  f32x4  __attribute__((ext_vector_type(4)));

__device__ __forceinline__ int row_off(int r) {
  if (r < NROW) return r*ND + (r >> 7)*LD2;
  int r2 = r - NROW;
  return r2*ND + (r2 >> 7)*LD2 + LD2;
}

// ---------------- K0: w1 -> w1t transpose + zero-init of fixup state -------
__global__ __launch_bounds__(256) void k0_w1t(const float* __restrict__ w1,
                                              __bf16* __restrict__ w1t,
                                              unsigned long long* __restrict__ amax2,
                                              unsigned* __restrict__ cntg) {
  __shared__ float tile[64][68];
  int idx = blockIdx.x*256 + threadIdx.x;
  if (idx < NROW) amax2[idx] = 0ull;
  if (idx == 0) *cntg = 0u;
  int kb = (blockIdx.x / 12) * 64, eb = (blockIdx.x % 12) * 64;
  int t = threadIdx.x;
  int r = t >> 2, c0 = (t & 3) * 16;
  #pragma unroll
  for (int j = 0; j < 4; j++) {
    f32x4 v = *(const f32x4*)(w1 + (kb + r)*ND + eb + c0 + j*4);
    *(f32x4*)&tile[r][c0 + j*4] = v;
  }
  __syncthreads();
  int e = t & 63, gi = t >> 6;
  int eg = eb + e;
  #pragma unroll
  for (int g2 = 0; g2 < 2; g2++) {
    int g = gi*2 + g2;
    bf16x8 o;
    #pragma unroll
    for (int j = 0; j < 8; j++) o[j] = (__bf16)tile[g*8 + j][e];
    int G = (kb >> 3) + (g ^ (eg & 7));        // bank swizzle for frag reads
    *(bf16x8*)(w1t + eg*ND + G*8) = o;
  }
}

// RNE round f32 bits to bf16 (kept in high 16 bits)
__device__ __forceinline__ unsigned rne_hi(unsigned u) {
  return (u + 0x7fffu + ((u >> 16) & 1u)) & 0xffff0000u;
}
// split f32x4 -> RNE-bf16 hi (packed) + exact-remainder lo (RNE-bf16, packed)
__device__ __forceinline__ void cvt4(f32x4 v, unsigned& hp0, unsigned& hp1,
                                     unsigned& lp0, unsigned& lp1, float& sq) {
  unsigned r0 = rne_hi(__float_as_uint(v[0]));
  unsigned r1 = rne_hi(__float_as_uint(v[1]));
  unsigned r2 = rne_hi(__float_as_uint(v[2]));
  unsigned r3 = rne_hi(__float_as_uint(v[3]));
  hp0 = r1 | (r0 >> 16);
  hp1 = r3 | (r2 >> 16);
  float l0 = v[0] - __uint_as_float(r0);       // exact (Dekker split)
  float l1 = v[1] - __uint_as_float(r1);
  float l2 = v[2] - __uint_as_float(r2);
  float l3 = v[3] - __uint_as_float(r3);
  lp0 = rne_hi(__float_as_uint(l1)) | (rne_hi(__float_as_uint(l0)) >> 16);
  lp1 = rne_hi(__float_as_uint(l3)) | (rne_hi(__float_as_uint(l2)) >> 16);
  sq += v[0]*v[0] + v[1]*v[1] + v[2]*v[2] + v[3]*v[3];
}

// ---------------- K2a: MFMA cosine screen + argmax + norms + rows8 export --
__global__ __launch_bounds__(512) void k2a_screen(
    const float* __restrict__ ctxall, float* __restrict__ norm,
    int* __restrict__ amax, unsigned* __restrict__ cntg,
    unsigned* __restrict__ list, __bf16* __restrict__ rows8) {
  __shared__ alignas(16) __bf16 tiles[2][4][128*32];   // [buf][ahi,alo,bhi,blo]
  __shared__ float einv_s[128];
  int bk = blockIdx.x;
  int t = threadIdx.x;
  int mat = t >> 8, row = (t >> 1) & 127, kh = (t & 1) * 16;
  const float* src = ctxall + bk*2*LD2 + mat*LD2 + row*ND + kh;
  __bf16* rbase8 = rows8 + ((mat ? NROW : 0) + bk*NL + row)*ND + kh;
  int w = t >> 6, lane = t & 63, quad = lane >> 4, eloc = lane & 15;

  f32x4 pv[4];
  #pragma unroll
  for (int i = 0; i < 4; i++) pv[i] = *(const f32x4*)(src + i*4);
  float sq = 0.f;
  f32x4 acc[8];
  #pragma unroll
  for (int ct = 0; ct < 8; ct++) acc[ct] = (f32x4){0,0,0,0};

  int p = 0;
  for (int kt = 0; kt < 24; kt++) {
    unsigned h0,h1,h2,h3, l0,l1,l2,l3;
    cvt4(pv[0], h0, h1, l0, l1, sq);
    cvt4(pv[1], h2, h3, l2, l3, sq);
    __bf16* hdst = &tiles[p][2*mat  ][row*32 + kh];
    __bf16* ldst = &tiles[p][2*mat+1][row*32 + kh];
    uint4* rdst = (uint4*)(rbase8 + kt*32);
    *(uint4*)hdst = make_uint4(h0,h1,h2,h3);
    *(uint4*)ldst = make_uint4(l0,l1,l2,l3);
    rdst[0] = make_uint4(h0,h1,h2,h3);          // hi-plane export for k3
    cvt4(pv[2], h0, h1, l0, l1, sq);
    cvt4(pv[3], h2, h3, l2, l3, sq);
    *((uint4*)hdst + 1) = make_uint4(h0,h1,h2,h3);
    *((uint4*)ldst + 1) = make_uint4(l0,l1,l2,l3);
    rdst[1] = make_uint4(h0,h1,h2,h3);
    __syncthreads();
    if (kt < 23) {
      const float* s2 = src + (kt+1)*32;
      #pragma unroll
      for (int i = 0; i < 4; i++) pv[i] = *(const f32x4*)(s2 + i*4);
    }
    bf16x8 ah = *(const bf16x8*)&tiles[p][0][(w*16+eloc)*32 + quad*8];
    bf16x8 al = *(const bf16x8*)&tiles[p][1][(w*16+eloc)*32 + quad*8];
    #pragma unroll
    for (int ct = 0; ct < 8; ct++) {
      bf16x8 bh = *(const bf16x8*)&tiles[p][2][(ct*16+eloc)*32 + quad*8];
      bf16x8 bl = *(const bf16x8*)&tiles[p][3][(ct*16+eloc)*32 + quad*8];
      acc[ct] = __builtin_amdgcn_mfma_f32_16x16x32_bf16(al, bh, acc[ct], 0, 0, 0);
      acc[ct] = __builtin_amdgcn_mfma_f32_16x16x32_bf16(ah, bl, acc[ct], 0, 0, 0);
      acc[ct] = __builtin_amdgcn_mfma_f32_16x16x32_bf16(ah, bh, acc[ct], 0, 0, 0);
    }
    p ^= 1;
  }

  float stot = sq + __shfl_xor(sq, 1);
  if ((t & 1) == 0) {
    float n = sqrtf(stot);
    if (mat == 0) norm[bk*NL + row] = n;
    else { norm[NROW + bk*NL + row] = n; einv_s[row] = 1.0f / n; }
  }
  __syncthreads();

  #pragma unroll
  for (int rr = 0; rr < 4; rr++) {
    float sc[8];
    float best = -3.0e38f; int bcol = 0;
    #pragma unroll
    for (int ct = 0; ct < 8; ct++) {
      sc[ct] = acc[ct][rr] * einv_s[ct*16 + eloc];
      int col = ct*16 + eloc;
      if (sc[ct] > best) { best = sc[ct]; bcol = col; }
    }
    #pragma unroll
    for (int m = 1; m < 16; m <<= 1) {
      float ov = __shfl_xor(best, m);
      int   oc = __shfl_xor(bcol, m);
      if (ov > best || (ov == best && oc < bcol)) { best = ov; bcol = oc; }
    }
    int grow = bk*NL + w*16 + quad*4 + rr;
    if (eloc == 0) amax[grow] = bcol;
    int cnt = 0;
    #pragma unroll
    for (int ct = 0; ct < 8; ct++) cnt += (sc[ct] >= best - THETA) ? 1 : 0;
    #pragma unroll
    for (int m = 1; m < 16; m <<= 1) cnt += __shfl_xor(cnt, m);
    if (cnt >= 2) {
      #pragma unroll
      for (int ct = 0; ct < 8; ct++) {
        if (sc[ct] >= best - THETA) {
          unsigned idx = atomicAdd(cntg, 1u);
          if (idx < CAP) list[idx] = ((unsigned)grow << 7) | (unsigned)(ct*16 + eloc);
        }
      }
    }
  }
}

// ---------------- K2b: exact f32 rescore of near-tie candidates ------------
__global__ __launch_bounds__(256) void k2b_rescore(
    const float* __restrict__ ctxall, const float* __restrict__ norm,
    const unsigned* __restrict__ cntg, const unsigned* __restrict__ list,
    unsigned long long* __restrict__ amax2) {
  unsigned n = *cntg; if (n > CAP) n = CAP;
  int lane = threadIdx.x & 63;
  unsigned wv = blockIdx.x*4 + (threadIdx.x >> 6);
  for (unsigned e = wv; e < n; e += 256) {
    unsigned ent = list[e];
    int row = (int)(ent >> 7), col = (int)(ent & 127);
    int bk = row >> 7;
    const float* a = ctxall + row_off(row);
    const float* b = ctxall + bk*2*LD2 + LD2 + col*ND;
    float d = 0.f;
    #pragma unroll
    for (int i = 0; i < 3; i++) {
      f32x4 va = *(const f32x4*)(a + lane*12 + i*4);
      f32x4 vb = *(const f32x4*)(b + lane*12 + i*4);
      d += va[0]*vb[0] + va[1]*vb[1] + va[2]*vb[2] + va[3]*vb[3];
    }
    #pragma unroll
    for (int m = 1; m < 64; m <<= 1) d += __shfl_xor(d, m);
    if (lane == 0) {
      float cn = norm[row], en = norm[NROW + bk*NL + col];
      float s = d / (cn*en + EPSF);
      unsigned su = __float_as_uint(s);
      unsigned ord = (su & 0x80000000u) ? ~su : (su | 0x80000000u);
      unsigned long long key = ((unsigned long long)ord << 32) | (unsigned)(127 - col);
      atomicMax(&amax2[row], key);
    }
  }
}

// ---------------- K3: fused MLP value per row (bf16 MFMA) ------------------
// 64 rows/wave (4 A-frag sets) -> each B ds_read_b128 feeds 4 MFMAs (32
// MAC/LDS-byte, halved LDS traffic). Rows read as bf16 from rows8 (no f32
// re-read, no conversion). Unnormalized rows: relu(rinv*y+b1) =
// rinv*relu(y + norm*b1), so norm folds into bias + final scale.
__global__ __launch_bounds__(256, 1) void k3_mlp(
    const __bf16* __restrict__ rows8, const float* __restrict__ norm,
    const __bf16* __restrict__ w1t, const float* __restrict__ b1,
    const float* __restrict__ w2, float* __restrict__ val) {
  __shared__ alignas(16) __bf16 btile[2][16*768];   // 2 x 24 KB w1t tiles
  int tid = threadIdx.x;
  int wave = tid >> 6, lane = tid & 63;
  int quad = lane >> 4, eloc = lane & 15;
  int rbase = blockIdx.x*256 + wave*64;

  // issue nt=0 stage; flies over the A-preload
  #pragma unroll
  for (int i = 0; i < 6; i++) {
    __builtin_amdgcn_global_load_lds(
      (const __attribute__((address_space(1))) unsigned int*)(w1t + (i*256 + tid)*8),
      (__attribute__((address_space(3))) unsigned int*)(&btile[0][0] + (i*256 + tid)*8),
      16, 0, 0);
  }

  bf16x8 afrag[4][24];                       // 64 rows x 768 k, 384 VGPR
  #pragma unroll
  for (int s = 0; s < 4; s++) {
    const __bf16* src = rows8 + (rbase + s*16 + eloc)*ND + quad*8;
    #pragma unroll
    for (int ks = 0; ks < 24; ks++)
      afrag[s][ks] = *(const bf16x8*)(src + ks*32);
  }
  float nrm[4][4];
  #pragma unroll
  for (int s = 0; s < 4; s++)
    #pragma unroll
    for (int rr = 0; rr < 4; rr++)
      nrm[s][rr] = norm[rbase + s*16 + quad*4 + rr];

  float oacc[4][4] = {{0,0,0,0},{0,0,0,0},{0,0,0,0},{0,0,0,0}};
  int p = 0;
  for (int nt = 0; nt < 48; nt++) {
    __syncthreads();                          // drains btile[p] loads
    if (nt < 47) {
      const __bf16* gsrc = w1t + (nt+1)*16*ND;
      #pragma unroll
      for (int i = 0; i < 6; i++) {
        __builtin_amdgcn_global_load_lds(
          (const __attribute__((address_space(1))) unsigned int*)(gsrc + (i*256 + tid)*8),
          (__attribute__((address_space(3))) unsigned int*)(&btile[p^1][0] + (i*256 + tid)*8),
          16, 0, 0);
      }
    }
    f32x4 h0 = {0,0,0,0}, h1 = {0,0,0,0}, h2 = {0,0,0,0}, h3 = {0,0,0,0};
    #pragma unroll
    for (int ks = 0; ks < 24; ks++) {
      int g = ks*4 + quad;
      bf16x8 bfrag = *(const bf16x8*)(&btile[p][0] + eloc*ND + ((g ^ (eloc & 7))*8));
      h0 = __builtin_amdgcn_mfma_f32_16x16x32_bf16(afrag[0][ks], bfrag, h0, 0, 0, 0);
      h1 = __builtin_amdgcn_mfma_f32_16x16x32_bf16(afrag[1][ks], bfrag, h1, 0, 0, 0);
      h2 = __builtin_amdgcn_mfma_f32_16x16x32_bf16(afrag[2][ks], bfrag, h2, 0, 0, 0);
      h3 = __builtin_amdgcn_mfma_f32_16x16x32_bf16(afrag[3][ks], bfrag, h3, 0, 0, 0);
    }
    float b1v = b1[nt*16 + eloc];
    float w2v = w2[nt*16 + eloc];
    #pragma unroll
    for (int rr = 0; rr < 4; rr++) {
      oacc[0][rr] += fmaxf(h0[rr] + b1v*nrm[0][rr], 0.f) * w2v;
      oacc[1][rr] += fmaxf(h1[rr] + b1v*nrm[1][rr], 0.f) * w2v;
      oacc[2][rr] += fmaxf(h2[rr] + b1v*nrm[2][rr], 0.f) * w2v;
      oacc[3][rr] += fmaxf(h3[rr] + b1v*nrm[3][rr], 0.f) * w2v;
    }
    p ^= 1;
  }
  #pragma unroll
  for (int m = 1; m < 16; m <<= 1)
    #pragma unroll
    for (int s = 0; s < 4; s++)
      #pragma unroll
      for (int rr = 0; rr < 4; rr++)
        oacc[s][rr] += __shfl_xor(oacc[s][rr], m);
  if (eloc == 0) {
    #pragma unroll
    for (int s = 0; s < 4; s++)
      #pragma unroll
      for (int rr = 0; rr < 4; rr++)
        val[rbase + s*16 + quad*4 + rr] = oacc[s][rr] / nrm[s][rr];
  }
}

// ---------------- K4: gather-add final output (with fixup override) --------
__global__ void k4_out(const float* __restrict__ val, const int* __restrict__ amax,
                       const unsigned long long* __restrict__ amax2,
                       const float* __restrict__ b2, float* __restrict__ out) {
  int i = blockIdx.x*256 + threadIdx.x;
  int bk = i >> 7;
  unsigned long long k = amax2[i];
  int a = k ? (127 - (int)(k & 127ull)) : amax[i];
  out[i] = val[i] + val[NROW + bk*NL + a] + 2.0f*b2[0];
}

extern "C" void kernel_launch(void* const* d_in, const int* in_sizes, int n_in,
                              void* d_out, int out_size, void* d_ws, size_t ws_size,
                              hipStream_t stream) {
  const float* ctxall = (const float*)d_in[0];
  const float* w1 = (const float*)d_in[1];
  const float* b1 = (const float*)d_in[2];
  const float* w2 = (const float*)d_in[3];
  const float* b2 = (const float*)d_in[4];
  float* out = (float*)d_out;

  char* ws = (char*)d_ws;
  float*    norm = (float*)ws;                        // [0, 262144)
  int*      amax = (int*)(ws + 262144);               // [262144, 393216)
  float*    val  = (float*)(ws + 393216);             // [393216, 655360)
  __bf16*   w1t  = (__bf16*)(ws + 655360);            // [655360, 1835008)
  unsigned long long* amax2 = (unsigned long long*)(ws + 1835008);  // 256 KB
  unsigned* cntg = (unsigned*)(ws + 2097152);         // 4 B
  unsigned* list = (unsigned*)(ws + 2097156);         // 64 KB
  __bf16*   rows8 = (__bf16*)(ws + 4194304);          // 100.7 MB bf16 rows

  hipLaunchKernelGGL(k0_w1t,     dim3(144),        dim3(256), 0, stream, w1, w1t, amax2, cntg);
  hipLaunchKernelGGL(k2a_screen, dim3(NBK),        dim3(512), 0, stream, ctxall, norm, amax, cntg, list, rows8);
  hipLaunchKernelGGL(k2b_rescore,dim3(64),         dim3(256), 0, stream, ctxall, norm, cntg, list, amax2);
  hipLaunchKernelGGL(k3_mlp,     dim3(256),        dim3(256), 0, stream, rows8, norm, w1t, b1, w2, val);
  hipLaunchKernelGGL(k4_out,     dim3(NROW/256),   dim3(256), 0, stream, val, amax, amax2, b2, out);
}

// Round 5
// 440.715 us; speedup vs baseline: 1.0048x; 1.0048x over previous
//
#include <hip/hip_runtime.h>
#include <hip/hip_bf16.h>
#include <stdint.h>

#define NB 4
#define NK 64
#define NL 128
#define ND 768
#define NBK (NB*NK)        // 256
#define NROW (NBK*NL)      // 32768
#define LD2 (NL*ND)        // 98304
#define EPSF 1e-8f
#define THETA 2e-3f
#define CAP 16384

typedef __bf16 bf16x8 __attribute__((ext_vector_type(8)));
typedef float  f32x4  __attribute__((ext_vector_type(4)));

__device__ __forceinline__ int row_off(int r) {
  if (r < NROW) return r*ND + (r >> 7)*LD2;
  int r2 = r - NROW;
  return r2*ND + (r2 >> 7)*LD2 + LD2;
}

// ---------------- K0: w1 -> w1t transpose + zero-init of fixup state -------
__global__ __launch_bounds__(256) void k0_w1t(const float* __restrict__ w1,
                                              __bf16* __restrict__ w1t,
                                              unsigned long long* __restrict__ amax2,
                                              unsigned* __restrict__ cntg) {
  __shared__ float tile[64][68];
  int idx = blockIdx.x*256 + threadIdx.x;
  if (idx < NROW) amax2[idx] = 0ull;
  if (idx == 0) *cntg = 0u;
  int kb = (blockIdx.x / 12) * 64, eb = (blockIdx.x % 12) * 64;
  int t = threadIdx.x;
  int r = t >> 2, c0 = (t & 3) * 16;
  #pragma unroll
  for (int j = 0; j < 4; j++) {
    f32x4 v = *(const f32x4*)(w1 + (kb + r)*ND + eb + c0 + j*4);
    *(f32x4*)&tile[r][c0 + j*4] = v;
  }
  __syncthreads();
  int e = t & 63, gi = t >> 6;
  int eg = eb + e;
  #pragma unroll
  for (int g2 = 0; g2 < 2; g2++) {
    int g = gi*2 + g2;
    bf16x8 o;
    #pragma unroll
    for (int j = 0; j < 8; j++) o[j] = (__bf16)tile[g*8 + j][e];
    int G = (kb >> 3) + (g ^ (eg & 7));        // bank swizzle for frag reads
    *(bf16x8*)(w1t + eg*ND + G*8) = o;
  }
}

// RNE round f32 bits to bf16 (kept in high 16 bits)
__device__ __forceinline__ unsigned rne_hi(unsigned u) {
  return (u + 0x7fffu + ((u >> 16) & 1u)) & 0xffff0000u;
}
// split f32x4 -> RNE-bf16 hi (packed) + exact-remainder lo (RNE-bf16, packed)
__device__ __forceinline__ void cvt4(f32x4 v, unsigned& hp0, unsigned& hp1,
                                     unsigned& lp0, unsigned& lp1, float& sq) {
  unsigned r0 = rne_hi(__float_as_uint(v[0]));
  unsigned r1 = rne_hi(__float_as_uint(v[1]));
  unsigned r2 = rne_hi(__float_as_uint(v[2]));
  unsigned r3 = rne_hi(__float_as_uint(v[3]));
  hp0 = r1 | (r0 >> 16);
  hp1 = r3 | (r2 >> 16);
  float l0 = v[0] - __uint_as_float(r0);       // exact (Dekker split)
  float l1 = v[1] - __uint_as_float(r1);
  float l2 = v[2] - __uint_as_float(r2);
  float l3 = v[3] - __uint_as_float(r3);
  lp0 = rne_hi(__float_as_uint(l1)) | (rne_hi(__float_as_uint(l0)) >> 16);
  lp1 = rne_hi(__float_as_uint(l3)) | (rne_hi(__float_as_uint(l2)) >> 16);
  sq += v[0]*v[0] + v[1]*v[1] + v[2]*v[2] + v[3]*v[3];
}

// ---------------- K2a: MFMA cosine screen + argmax + norms + rows8 export --
__global__ __launch_bounds__(512) void k2a_screen(
    const float* __restrict__ ctxall, float* __restrict__ norm,
    int* __restrict__ amax, unsigned* __restrict__ cntg,
    unsigned* __restrict__ list, __bf16* __restrict__ rows8) {
  __shared__ alignas(16) __bf16 tiles[2][4][128*32];   // [buf][ahi,alo,bhi,blo]
  __shared__ float einv_s[128];
  int bk = blockIdx.x;
  int t = threadIdx.x;
  int mat = t >> 8, row = (t >> 1) & 127, kh = (t & 1) * 16;
  const float* src = ctxall + bk*2*LD2 + mat*LD2 + row*ND + kh;
  __bf16* rbase8 = rows8 + ((mat ? NROW : 0) + bk*NL + row)*ND + kh;
  int w = t >> 6, lane = t & 63, quad = lane >> 4, eloc = lane & 15;

  f32x4 pv[4];
  #pragma unroll
  for (int i = 0; i < 4; i++) pv[i] = *(const f32x4*)(src + i*4);
  float sq = 0.f;
  f32x4 acc[8];
  #pragma unroll
  for (int ct = 0; ct < 8; ct++) acc[ct] = (f32x4){0,0,0,0};

  int p = 0;
  for (int kt = 0; kt < 24; kt++) {
    unsigned h0,h1,h2,h3, l0,l1,l2,l3;
    cvt4(pv[0], h0, h1, l0, l1, sq);
    cvt4(pv[1], h2, h3, l2, l3, sq);
    __bf16* hdst = &tiles[p][2*mat  ][row*32 + kh];
    __bf16* ldst = &tiles[p][2*mat+1][row*32 + kh];
    uint4* rdst = (uint4*)(rbase8 + kt*32);
    *(uint4*)hdst = make_uint4(h0,h1,h2,h3);
    *(uint4*)ldst = make_uint4(l0,l1,l2,l3);
    rdst[0] = make_uint4(h0,h1,h2,h3);          // hi-plane export for k3
    cvt4(pv[2], h0, h1, l0, l1, sq);
    cvt4(pv[3], h2, h3, l2, l3, sq);
    *((uint4*)hdst + 1) = make_uint4(h0,h1,h2,h3);
    *((uint4*)ldst + 1) = make_uint4(l0,l1,l2,l3);
    rdst[1] = make_uint4(h0,h1,h2,h3);
    __syncthreads();
    if (kt < 23) {
      const float* s2 = src + (kt+1)*32;
      #pragma unroll
      for (int i = 0; i < 4; i++) pv[i] = *(const f32x4*)(s2 + i*4);
    }
    bf16x8 ah = *(const bf16x8*)&tiles[p][0][(w*16+eloc)*32 + quad*8];
    bf16x8 al = *(const bf16x8*)&tiles[p][1][(w*16+eloc)*32 + quad*8];
    #pragma unroll
    for (int ct = 0; ct < 8; ct++) {
      bf16x8 bh = *(const bf16x8*)&tiles[p][2][(ct*16+eloc)*32 + quad*8];
      bf16x8 bl = *(const bf16x8*)&tiles[p][3][(ct*16+eloc)*32 + quad*8];
      acc[ct] = __builtin_amdgcn_mfma_f32_16x16x32_bf16(al, bh, acc[ct], 0, 0, 0);
      acc[ct] = __builtin_amdgcn_mfma_f32_16x16x32_bf16(ah, bl, acc[ct], 0, 0, 0);
      acc[ct] = __builtin_amdgcn_mfma_f32_16x16x32_bf16(ah, bh, acc[ct], 0, 0, 0);
    }
    p ^= 1;
  }

  float stot = sq + __shfl_xor(sq, 1);
  if ((t & 1) == 0) {
    float n = sqrtf(stot);
    if (mat == 0) norm[bk*NL + row] = n;
    else { norm[NROW + bk*NL + row] = n; einv_s[row] = 1.0f / n; }
  }
  __syncthreads();

  #pragma unroll
  for (int rr = 0; rr < 4; rr++) {
    float sc[8];
    float best = -3.0e38f; int bcol = 0;
    #pragma unroll
    for (int ct = 0; ct < 8; ct++) {
      sc[ct] = acc[ct][rr] * einv_s[ct*16 + eloc];
      int col = ct*16 + eloc;
      if (sc[ct] > best) { best = sc[ct]; bcol = col; }
    }
    #pragma unroll
    for (int m = 1; m < 16; m <<= 1) {
      float ov = __shfl_xor(best, m);
      int   oc = __shfl_xor(bcol, m);
      if (ov > best || (ov == best && oc < bcol)) { best = ov; bcol = oc; }
    }
    int grow = bk*NL + w*16 + quad*4 + rr;
    if (eloc == 0) amax[grow] = bcol;
    int cnt = 0;
    #pragma unroll
    for (int ct = 0; ct < 8; ct++) cnt += (sc[ct] >= best - THETA) ? 1 : 0;
    #pragma unroll
    for (int m = 1; m < 16; m <<= 1) cnt += __shfl_xor(cnt, m);
    if (cnt >= 2) {
      #pragma unroll
      for (int ct = 0; ct < 8; ct++) {
        if (sc[ct] >= best - THETA) {
          unsigned idx = atomicAdd(cntg, 1u);
          if (idx < CAP) list[idx] = ((unsigned)grow << 7) | (unsigned)(ct*16 + eloc);
        }
      }
    }
  }
}

// ---------------- K2b: exact f32 rescore of near-tie candidates ------------
__global__ __launch_bounds__(256) void k2b_rescore(
    const float* __restrict__ ctxall, const float* __restrict__ norm,
    const unsigned* __restrict__ cntg, const unsigned* __restrict__ list,
    unsigned long long* __restrict__ amax2) {
  unsigned n = *cntg; if (n > CAP) n = CAP;
  int lane = threadIdx.x & 63;
  unsigned wv = blockIdx.x*4 + (threadIdx.x >> 6);
  for (unsigned e = wv; e < n; e += 256) {
    unsigned ent = list[e];
    int row = (int)(ent >> 7), col = (int)(ent & 127);
    int bk = row >> 7;
    const float* a = ctxall + row_off(row);
    const float* b = ctxall + bk*2*LD2 + LD2 + col*ND;
    float d = 0.f;
    #pragma unroll
    for (int i = 0; i < 3; i++) {
      f32x4 va = *(const f32x4*)(a + lane*12 + i*4);
      f32x4 vb = *(const f32x4*)(b + lane*12 + i*4);
      d += va[0]*vb[0] + va[1]*vb[1] + va[2]*vb[2] + va[3]*vb[3];
    }
    #pragma unroll
    for (int m = 1; m < 64; m <<= 1) d += __shfl_xor(d, m);
    if (lane == 0) {
      float cn = norm[row], en = norm[NROW + bk*NL + col];
      float s = d / (cn*en + EPSF);
      unsigned su = __float_as_uint(s);
      unsigned ord = (su & 0x80000000u) ? ~su : (su | 0x80000000u);
      unsigned long long key = ((unsigned long long)ord << 32) | (unsigned)(127 - col);
      atomicMax(&amax2[row], key);
    }
  }
}

// ---------------- K3: fused MLP value per row (bf16 MFMA) ------------------
// 32 rows/wave (2 A-frag sets = 96 VGPR for A: PROVEN register-resident in
// r3; the r4 4-set variant overflowed and the compiler sank the loads into
// the nt-loop -> 4.8 GB L2 re-read, 123 us). Rows read as bf16 from rows8.
// Unnormalized rows: relu(rinv*y+b1) = rinv*relu(y + norm*b1).
__global__ __launch_bounds__(256, 2) void k3_mlp(
    const __bf16* __restrict__ rows8, const float* __restrict__ norm,
    const __bf16* __restrict__ w1t, const float* __restrict__ b1,
    const float* __restrict__ w2, float* __restrict__ val) {
  __shared__ alignas(16) __bf16 btile[2][16*768];   // 2 x 24 KB w1t tiles
  int tid = threadIdx.x;
  int wave = tid >> 6, lane = tid & 63;
  int quad = lane >> 4, eloc = lane & 15;
  int rbase = blockIdx.x*128 + wave*32;

  // issue nt=0 stage; flies over the A-preload
  #pragma unroll
  for (int i = 0; i < 6; i++) {
    __builtin_amdgcn_global_load_lds(
      (const __attribute__((address_space(1))) unsigned int*)(w1t + (i*256 + tid)*8),
      (__attribute__((address_space(3))) unsigned int*)(&btile[0][0] + (i*256 + tid)*8),
      16, 0, 0);
  }

  bf16x8 afrag[2][24];                       // 32 rows x 768 k = 96 VGPR
  #pragma unroll
  for (int s = 0; s < 2; s++) {
    const __bf16* src = rows8 + (rbase + s*16 + eloc)*ND + quad*8;
    #pragma unroll
    for (int ks = 0; ks < 24; ks++)
      afrag[s][ks] = *(const bf16x8*)(src + ks*32);
  }
  float nrm[2][4];
  #pragma unroll
  for (int s = 0; s < 2; s++)
    #pragma unroll
    for (int rr = 0; rr < 4; rr++)
      nrm[s][rr] = norm[rbase + s*16 + quad*4 + rr];

  float oacc[2][4] = {{0,0,0,0},{0,0,0,0}};
  int p = 0;
  for (int nt = 0; nt < 48; nt++) {
    __syncthreads();                          // drains btile[p] loads
    if (nt < 47) {
      const __bf16* gsrc = w1t + (nt+1)*16*ND;
      #pragma unroll
      for (int i = 0; i < 6; i++) {
        __builtin_amdgcn_global_load_lds(
          (const __attribute__((address_space(1))) unsigned int*)(gsrc + (i*256 + tid)*8),
          (__attribute__((address_space(3))) unsigned int*)(&btile[p^1][0] + (i*256 + tid)*8),
          16, 0, 0);
      }
    }
    f32x4 h0 = {0,0,0,0}, h1 = {0,0,0,0};
    #pragma unroll
    for (int ks = 0; ks < 24; ks++) {
      int g = ks*4 + quad;
      bf16x8 bfrag = *(const bf16x8*)(&btile[p][0] + eloc*ND + ((g ^ (eloc & 7))*8));
      h0 = __builtin_amdgcn_mfma_f32_16x16x32_bf16(afrag[0][ks], bfrag, h0, 0, 0, 0);
      h1 = __builtin_amdgcn_mfma_f32_16x16x32_bf16(afrag[1][ks], bfrag, h1, 0, 0, 0);
    }
    float b1v = b1[nt*16 + eloc];
    float w2v = w2[nt*16 + eloc];
    #pragma unroll
    for (int rr = 0; rr < 4; rr++) {
      oacc[0][rr] += fmaxf(h0[rr] + b1v*nrm[0][rr], 0.f) * w2v;
      oacc[1][rr] += fmaxf(h1[rr] + b1v*nrm[1][rr], 0.f) * w2v;
    }
    p ^= 1;
  }
  #pragma unroll
  for (int m = 1; m < 16; m <<= 1)
    #pragma unroll
    for (int s = 0; s < 2; s++)
      #pragma unroll
      for (int rr = 0; rr < 4; rr++)
        oacc[s][rr] += __shfl_xor(oacc[s][rr], m);
  if (eloc == 0) {
    #pragma unroll
    for (int s = 0; s < 2; s++)
      #pragma unroll
      for (int rr = 0; rr < 4; rr++)
        val[rbase + s*16 + quad*4 + rr] = oacc[s][rr] / nrm[s][rr];
  }
}

// ---------------- K4: gather-add final output (with fixup override) --------
__global__ void k4_out(const float* __restrict__ val, const int* __restrict__ amax,
                       const unsigned long long* __restrict__ amax2,
                       const float* __restrict__ b2, float* __restrict__ out) {
  int i = blockIdx.x*256 + threadIdx.x;
  int bk = i >> 7;
  unsigned long long k = amax2[i];
  int a = k ? (127 - (int)(k & 127ull)) : amax[i];
  out[i] = val[i] + val[NROW + bk*NL + a] + 2.0f*b2[0];
}

extern "C" void kernel_launch(void* const* d_in, const int* in_sizes, int n_in,
                              void* d_out, int out_size, void* d_ws, size_t ws_size,
                              hipStream_t stream) {
  const float* ctxall = (const float*)d_in[0];
  const float* w1 = (const float*)d_in[1];
  const float* b1 = (const float*)d_in[2];
  const float* w2 = (const float*)d_in[3];
  const float* b2 = (const float*)d_in[4];
  float* out = (float*)d_out;

  char* ws = (char*)d_ws;
  float*    norm = (float*)ws;                        // [0, 262144)
  int*      amax = (int*)(ws + 262144);               // [262144, 393216)
  float*    val  = (float*)(ws + 393216);             // [393216, 655360)
  __bf16*   w1t  = (__bf16*)(ws + 655360);            // [655360, 1835008)
  unsigned long long* amax2 = (unsigned long long*)(ws + 1835008);  // 256 KB
  unsigned* cntg = (unsigned*)(ws + 2097152);         // 4 B
  unsigned* list = (unsigned*)(ws + 2097156);         // 64 KB
  __bf16*   rows8 = (__bf16*)(ws + 4194304);          // 100.7 MB bf16 rows

  hipLaunchKernelGGL(k0_w1t,     dim3(144),        dim3(256), 0, stream, w1, w1t, amax2, cntg);
  hipLaunchKernelGGL(k2a_screen, dim3(NBK),        dim3(512), 0, stream, ctxall, norm, amax, cntg, list, rows8);
  hipLaunchKernelGGL(k2b_rescore,dim3(64),         dim3(256), 0, stream, ctxall, norm, cntg, list, amax2);
  hipLaunchKernelGGL(k3_mlp,     dim3(512),        dim3(256), 0, stream, rows8, norm, w1t, b1, w2, val);
  hipLaunchKernelGGL(k4_out,     dim3(NROW/256),   dim3(256), 0, stream, val, amax, amax2, b2, out);
}

// Round 6
// 405.904 us; speedup vs baseline: 1.0910x; 1.0858x over previous
//
#include <hip/hip_runtime.h>
#include <hip/hip_bf16.h>
#include <stdint.h>

#define NB 4
#define NK 64
#define NL 128
#define ND 768
#define NBK (NB*NK)        // 256
#define NROW (NBK*NL)      // 32768
#define LD2 (NL*ND)        // 98304
#define EPSF 1e-8f
#define THETA 2e-3f
#define CAP 16384

typedef __bf16 bf16x8 __attribute__((ext_vector_type(8)));
typedef float  f32x4  __attribute__((ext_vector_type(4)));

__device__ __forceinline__ int row_off(int r) {
  if (r < NROW) return r*ND + (r >> 7)*LD2;
  int r2 = r - NROW;
  return r2*ND + (r2 >> 7)*LD2 + LD2;
}

// ---------------- K0: w1 -> w1t2 + zero-init of fixup state ----------------
// w1t2 layout = [nt(48)][ks(24)][lane(64)][8 bf16] where lane=(quad,eloc),
// element = B[k=ks*32+quad*8+j][e=nt*16+eloc]. k3's wave then reads one
// CONTIGUOUS 1024 B block per ds_read_b128 (addr = uniform + lane*16):
// structurally zero bank conflicts (r5 measured 9.4M conflict cycles on the
// old XOR-swizzled row-major layout).
__global__ __launch_bounds__(256) void k0_w1t(const float* __restrict__ w1,
                                              __bf16* __restrict__ w1t2,
                                              unsigned long long* __restrict__ amax2,
                                              unsigned* __restrict__ cntg) {
  __shared__ float tile[64][68];
  int idx = blockIdx.x*256 + threadIdx.x;
  if (idx < NROW) amax2[idx] = 0ull;
  if (idx == 0) *cntg = 0u;
  int kb = blockIdx.x / 12, eb = blockIdx.x % 12;   // 64x64 (k,e) tile
  int t = threadIdx.x;
  int r = t >> 2, c0 = (t & 3) * 16;
  #pragma unroll
  for (int j = 0; j < 4; j++) {
    f32x4 v = *(const f32x4*)(w1 + (kb*64 + r)*ND + eb*64 + c0 + j*4);
    *(f32x4*)&tile[r][c0 + j*4] = v;
  }
  __syncthreads();
  int el = t & 63, gi = t >> 6;
  int nt = eb*4 + (el >> 4), eloc = el & 15;
  #pragma unroll
  for (int g2 = 0; g2 < 2; g2++) {
    int kl = gi*16 + g2*8;                          // 8 consecutive k
    bf16x8 o;
    #pragma unroll
    for (int j = 0; j < 8; j++) o[j] = (__bf16)tile[kl + j][el];
    int ks = kb*2 + (kl >> 5), quad = (kl >> 3) & 3;
    *(bf16x8*)(w1t2 + nt*12288 + ks*512 + quad*128 + eloc*8) = o;
  }
}

// RNE round f32 bits to bf16 (kept in high 16 bits)
__device__ __forceinline__ unsigned rne_hi(unsigned u) {
  return (u + 0x7fffu + ((u >> 16) & 1u)) & 0xffff0000u;
}
// split f32x4 -> RNE-bf16 hi (packed) + exact-remainder lo (RNE-bf16, packed)
__device__ __forceinline__ void cvt4(f32x4 v, unsigned& hp0, unsigned& hp1,
                                     unsigned& lp0, unsigned& lp1, float& sq) {
  unsigned r0 = rne_hi(__float_as_uint(v[0]));
  unsigned r1 = rne_hi(__float_as_uint(v[1]));
  unsigned r2 = rne_hi(__float_as_uint(v[2]));
  unsigned r3 = rne_hi(__float_as_uint(v[3]));
  hp0 = r1 | (r0 >> 16);
  hp1 = r3 | (r2 >> 16);
  float l0 = v[0] - __uint_as_float(r0);       // exact (Dekker split)
  float l1 = v[1] - __uint_as_float(r1);
  float l2 = v[2] - __uint_as_float(r2);
  float l3 = v[3] - __uint_as_float(r3);
  lp0 = rne_hi(__float_as_uint(l1)) | (rne_hi(__float_as_uint(l0)) >> 16);
  lp1 = rne_hi(__float_as_uint(l3)) | (rne_hi(__float_as_uint(l2)) >> 16);
  sq += v[0]*v[0] + v[1]*v[1] + v[2]*v[2] + v[3]*v[3];
}

// ---------------- K2a: MFMA cosine screen + argmax + norms + rows8 export --
__global__ __launch_bounds__(512) void k2a_screen(
    const float* __restrict__ ctxall, float* __restrict__ norm,
    int* __restrict__ amax, unsigned* __restrict__ cntg,
    unsigned* __restrict__ list, __bf16* __restrict__ rows8) {
  __shared__ alignas(16) __bf16 tiles[2][4][128*32];   // [buf][ahi,alo,bhi,blo]
  __shared__ float einv_s[128];
  int bk = blockIdx.x;
  int t = threadIdx.x;
  int mat = t >> 8, row = (t >> 1) & 127, kh = (t & 1) * 16;
  const float* src = ctxall + bk*2*LD2 + mat*LD2 + row*ND + kh;
  __bf16* rbase8 = rows8 + ((mat ? NROW : 0) + bk*NL + row)*ND + kh;
  int w = t >> 6, lane = t & 63, quad = lane >> 4, eloc = lane & 15;

  f32x4 pv[4];
  #pragma unroll
  for (int i = 0; i < 4; i++) pv[i] = *(const f32x4*)(src + i*4);
  float sq = 0.f;
  f32x4 acc[8];
  #pragma unroll
  for (int ct = 0; ct < 8; ct++) acc[ct] = (f32x4){0,0,0,0};

  int p = 0;
  for (int kt = 0; kt < 24; kt++) {
    unsigned h0,h1,h2,h3, l0,l1,l2,l3;
    cvt4(pv[0], h0, h1, l0, l1, sq);
    cvt4(pv[1], h2, h3, l2, l3, sq);
    __bf16* hdst = &tiles[p][2*mat  ][row*32 + kh];
    __bf16* ldst = &tiles[p][2*mat+1][row*32 + kh];
    uint4* rdst = (uint4*)(rbase8 + kt*32);
    *(uint4*)hdst = make_uint4(h0,h1,h2,h3);
    *(uint4*)ldst = make_uint4(l0,l1,l2,l3);
    rdst[0] = make_uint4(h0,h1,h2,h3);          // hi-plane export for k3
    cvt4(pv[2], h0, h1, l0, l1, sq);
    cvt4(pv[3], h2, h3, l2, l3, sq);
    *((uint4*)hdst + 1) = make_uint4(h0,h1,h2,h3);
    *((uint4*)ldst + 1) = make_uint4(l0,l1,l2,l3);
    rdst[1] = make_uint4(h0,h1,h2,h3);
    __syncthreads();
    if (kt < 23) {
      const float* s2 = src + (kt+1)*32;
      #pragma unroll
      for (int i = 0; i < 4; i++) pv[i] = *(const f32x4*)(s2 + i*4);
    }
    bf16x8 ah = *(const bf16x8*)&tiles[p][0][(w*16+eloc)*32 + quad*8];
    bf16x8 al = *(const bf16x8*)&tiles[p][1][(w*16+eloc)*32 + quad*8];
    #pragma unroll
    for (int ct = 0; ct < 8; ct++) {
      bf16x8 bh = *(const bf16x8*)&tiles[p][2][(ct*16+eloc)*32 + quad*8];
      bf16x8 bl = *(const bf16x8*)&tiles[p][3][(ct*16+eloc)*32 + quad*8];
      acc[ct] = __builtin_amdgcn_mfma_f32_16x16x32_bf16(al, bh, acc[ct], 0, 0, 0);
      acc[ct] = __builtin_amdgcn_mfma_f32_16x16x32_bf16(ah, bl, acc[ct], 0, 0, 0);
      acc[ct] = __builtin_amdgcn_mfma_f32_16x16x32_bf16(ah, bh, acc[ct], 0, 0, 0);
    }
    p ^= 1;
  }

  float stot = sq + __shfl_xor(sq, 1);
  if ((t & 1) == 0) {
    float n = sqrtf(stot);
    if (mat == 0) norm[bk*NL + row] = n;
    else { norm[NROW + bk*NL + row] = n; einv_s[row] = 1.0f / n; }
  }
  __syncthreads();

  #pragma unroll
  for (int rr = 0; rr < 4; rr++) {
    float sc[8];
    float best = -3.0e38f; int bcol = 0;
    #pragma unroll
    for (int ct = 0; ct < 8; ct++) {
      sc[ct] = acc[ct][rr] * einv_s[ct*16 + eloc];
      int col = ct*16 + eloc;
      if (sc[ct] > best) { best = sc[ct]; bcol = col; }
    }
    #pragma unroll
    for (int m = 1; m < 16; m <<= 1) {
      float ov = __shfl_xor(best, m);
      int   oc = __shfl_xor(bcol, m);
      if (ov > best || (ov == best && oc < bcol)) { best = ov; bcol = oc; }
    }
    int grow = bk*NL + w*16 + quad*4 + rr;
    if (eloc == 0) amax[grow] = bcol;
    int cnt = 0;
    #pragma unroll
    for (int ct = 0; ct < 8; ct++) cnt += (sc[ct] >= best - THETA) ? 1 : 0;
    #pragma unroll
    for (int m = 1; m < 16; m <<= 1) cnt += __shfl_xor(cnt, m);
    if (cnt >= 2) {
      #pragma unroll
      for (int ct = 0; ct < 8; ct++) {
        if (sc[ct] >= best - THETA) {
          unsigned idx = atomicAdd(cntg, 1u);
          if (idx < CAP) list[idx] = ((unsigned)grow << 7) | (unsigned)(ct*16 + eloc);
        }
      }
    }
  }
}

// ---------------- K2b: exact f32 rescore of near-tie candidates ------------
__global__ __launch_bounds__(256) void k2b_rescore(
    const float* __restrict__ ctxall, const float* __restrict__ norm,
    const unsigned* __restrict__ cntg, const unsigned* __restrict__ list,
    unsigned long long* __restrict__ amax2) {
  unsigned n = *cntg; if (n > CAP) n = CAP;
  int lane = threadIdx.x & 63;
  unsigned wv = blockIdx.x*4 + (threadIdx.x >> 6);
  for (unsigned e = wv; e < n; e += 256) {
    unsigned ent = list[e];
    int row = (int)(ent >> 7), col = (int)(ent & 127);
    int bk = row >> 7;
    const float* a = ctxall + row_off(row);
    const float* b = ctxall + bk*2*LD2 + LD2 + col*ND;
    float d = 0.f;
    #pragma unroll
    for (int i = 0; i < 3; i++) {
      f32x4 va = *(const f32x4*)(a + lane*12 + i*4);
      f32x4 vb = *(const f32x4*)(b + lane*12 + i*4);
      d += va[0]*vb[0] + va[1]*vb[1] + va[2]*vb[2] + va[3]*vb[3];
    }
    #pragma unroll
    for (int m = 1; m < 64; m <<= 1) d += __shfl_xor(d, m);
    if (lane == 0) {
      float cn = norm[row], en = norm[NROW + bk*NL + col];
      float s = d / (cn*en + EPSF);
      unsigned su = __float_as_uint(s);
      unsigned ord = (su & 0x80000000u) ? ~su : (su | 0x80000000u);
      unsigned long long key = ((unsigned long long)ord << 32) | (unsigned)(127 - col);
      atomicMax(&amax2[row], key);
    }
  }
}

// ---------------- K3: fused MLP value per row (bf16 MFMA) ------------------
// 32 rows/wave, afrag = 192 VGPR held resident: amdgpu_waves_per_eu(2,2)
// pins occupancy at 2 waves/EU so the allocator gets the full 256-VGPR
// budget (r4/r5 failure: allocator targeted 128 regs and sank the A loads
// into the nt-loop -> ~4.8 GB L2 re-read, 120 us). B-frags read as one
// contiguous 1024 B/wave ds_read_b128 from the w1t2 layout (0 conflicts).
__global__ __launch_bounds__(256)
__attribute__((amdgpu_waves_per_eu(2, 2)))
void k3_mlp(
    const __bf16* __restrict__ rows8, const float* __restrict__ norm,
    const __bf16* __restrict__ w1t2, const float* __restrict__ b1,
    const float* __restrict__ w2, float* __restrict__ val) {
  __shared__ alignas(16) __bf16 btile[2][12288];   // 2 x 24 KB w1t2 tiles
  int tid = threadIdx.x;
  int wave = tid >> 6, lane = tid & 63;
  int quad = lane >> 4, eloc = lane & 15;
  int rbase = blockIdx.x*128 + wave*32;

  // issue nt=0 stage; flies over the A-preload
  #pragma unroll
  for (int i = 0; i < 6; i++) {
    __builtin_amdgcn_global_load_lds(
      (const __attribute__((address_space(1))) unsigned int*)(w1t2 + (i*256 + tid)*8),
      (__attribute__((address_space(3))) unsigned int*)(&btile[0][0] + (i*256 + tid)*8),
      16, 0, 0);
  }

  bf16x8 afrag[2][24];                       // 32 rows x 768 k = 192 VGPR
  #pragma unroll
  for (int s = 0; s < 2; s++) {
    const __bf16* src = rows8 + (rbase + s*16 + eloc)*ND + quad*8;
    #pragma unroll
    for (int ks = 0; ks < 24; ks++)
      afrag[s][ks] = *(const bf16x8*)(src + ks*32);
  }
  float nrm[2][4];
  #pragma unroll
  for (int s = 0; s < 2; s++)
    #pragma unroll
    for (int rr = 0; rr < 4; rr++)
      nrm[s][rr] = norm[rbase + s*16 + quad*4 + rr];

  float oacc[2][4] = {{0,0,0,0},{0,0,0,0}};
  int p = 0;
  for (int nt = 0; nt < 48; nt++) {
    __syncthreads();                          // drains btile[p] loads
    if (nt < 47) {
      const __bf16* gsrc = w1t2 + (nt+1)*12288;
      #pragma unroll
      for (int i = 0; i < 6; i++) {
        __builtin_amdgcn_global_load_lds(
          (const __attribute__((address_space(1))) unsigned int*)(gsrc + (i*256 + tid)*8),
          (__attribute__((address_space(3))) unsigned int*)(&btile[p^1][0] + (i*256 + tid)*8),
          16, 0, 0);
      }
    }
    f32x4 h0 = {0,0,0,0}, h1 = {0,0,0,0};
    #pragma unroll
    for (int ks = 0; ks < 24; ks++) {
      // contiguous per-wave 1024 B: uniform + lane*16 -> conflict-free
      bf16x8 bfrag = *(const bf16x8*)(&btile[p][0] + ks*512 + lane*8);
      h0 = __builtin_amdgcn_mfma_f32_16x16x32_bf16(afrag[0][ks], bfrag, h0, 0, 0, 0);
      h1 = __builtin_amdgcn_mfma_f32_16x16x32_bf16(afrag[1][ks], bfrag, h1, 0, 0, 0);
    }
    float b1v = b1[nt*16 + eloc];
    float w2v = w2[nt*16 + eloc];
    #pragma unroll
    for (int rr = 0; rr < 4; rr++) {
      oacc[0][rr] += fmaxf(h0[rr] + b1v*nrm[0][rr], 0.f) * w2v;
      oacc[1][rr] += fmaxf(h1[rr] + b1v*nrm[1][rr], 0.f) * w2v;
    }
    p ^= 1;
  }
  #pragma unroll
  for (int m = 1; m < 16; m <<= 1)
    #pragma unroll
    for (int s = 0; s < 2; s++)
      #pragma unroll
      for (int rr = 0; rr < 4; rr++)
        oacc[s][rr] += __shfl_xor(oacc[s][rr], m);
  if (eloc == 0) {
    #pragma unroll
    for (int s = 0; s < 2; s++)
      #pragma unroll
      for (int rr = 0; rr < 4; rr++)
        val[rbase + s*16 + quad*4 + rr] = oacc[s][rr] / nrm[s][rr];
  }
}

// ---------------- K4: gather-add final output (with fixup override) --------
__global__ void k4_out(const float* __restrict__ val, const int* __restrict__ amax,
                       const unsigned long long* __restrict__ amax2,
                       const float* __restrict__ b2, float* __restrict__ out) {
  int i = blockIdx.x*256 + threadIdx.x;
  int bk = i >> 7;
  unsigned long long k = amax2[i];
  int a = k ? (127 - (int)(k & 127ull)) : amax[i];
  out[i] = val[i] + val[NROW + bk*NL + a] + 2.0f*b2[0];
}

extern "C" void kernel_launch(void* const* d_in, const int* in_sizes, int n_in,
                              void* d_out, int out_size, void* d_ws, size_t ws_size,
                              hipStream_t stream) {
  const float* ctxall = (const float*)d_in[0];
  const float* w1 = (const float*)d_in[1];
  const float* b1 = (const float*)d_in[2];
  const float* w2 = (const float*)d_in[3];
  const float* b2 = (const float*)d_in[4];
  float* out = (float*)d_out;

  char* ws = (char*)d_ws;
  float*    norm = (float*)ws;                        // [0, 262144)
  int*      amax = (int*)(ws + 262144);               // [262144, 393216)
  float*    val  = (float*)(ws + 393216);             // [393216, 655360)
  __bf16*   w1t2 = (__bf16*)(ws + 655360);            // [655360, 1835008)
  unsigned long long* amax2 = (unsigned long long*)(ws + 1835008);  // 256 KB
  unsigned* cntg = (unsigned*)(ws + 2097152);         // 4 B
  unsigned* list = (unsigned*)(ws + 2097156);         // 64 KB
  __bf16*   rows8 = (__bf16*)(ws + 4194304);          // 100.7 MB bf16 rows

  hipLaunchKernelGGL(k0_w1t,     dim3(144),        dim3(256), 0, stream, w1, w1t2, amax2, cntg);
  hipLaunchKernelGGL(k2a_screen, dim3(NBK),        dim3(512), 0, stream, ctxall, norm, amax, cntg, list, rows8);
  hipLaunchKernelGGL(k2b_rescore,dim3(64),         dim3(256), 0, stream, ctxall, norm, cntg, list, amax2);
  hipLaunchKernelGGL(k3_mlp,     dim3(512),        dim3(256), 0, stream, rows8, norm, w1t2, b1, w2, val);
  hipLaunchKernelGGL(k4_out,     dim3(NROW/256),   dim3(256), 0, stream, val, amax, amax2, b2, out);
}